// Round 11
// baseline (986.759 us; speedup 1.0000x reference)
//
#include <hip/hip_runtime.h>
#include <math.h>

// Round 11: rt=4 (64 rows/wave) split-fp16 3-term MFMA.
//   - Halves L2 weight traffic vs rt=2 (each W frag feeds 4 row-tiles) and
//     quadruples MFMA work per load batch (84 MFMA/s-step ~ 1600 cyc >> L2
//     ~300 cyc latency) -> latency amortized without register double-buffers
//     (round-10 lesson: forced dbuf -> 326 MB scratch spill traffic).
//   - 256 thr / 4 waves / 256 rows per block; X hi/lo fp16 planes = 128 KB
//     -> 1 block/CU, 4 waves (1/SIMD). No barriers in the layer loop
//     (wave-private rows) so low occupancy costs no sync stalls.
//   - L0 fixed: W0 columns in per-thread registers from GLOBAL (round 9's
//     w0s scalar LDS reads were 8-way bank conflicts x 192 reads/thread).
//   - launch_bounds(256,1): VGPR cap 512, live set ~220, no spills.
// Carried: HW transcendentals, bias folded at k=100 (X col 100 == 1.0),
// plane-separated hi/lo fp16 LDS, ((m&7)<<4) XOR swizzle, term-outer MFMAs.

typedef _Float16 half8 __attribute__((ext_vector_type(8)));
typedef _Float16 half4v __attribute__((ext_vector_type(4)));
typedef float f32x4 __attribute__((ext_vector_type(4)));

#define TPB 256
#define RPB 256

__device__ __forceinline__ float sp100(float x) {
    // softplus(100x)/100 = max(x,0) + ln2/100 * log2(1 + 2^(-(100/ln2)*|x|))
    float t = __builtin_amdgcn_exp2f(-144.26950408889634f * fabsf(x));
    return fmaxf(x, 0.0f) + 0.0069314718055994531f * __builtin_amdgcn_logf(1.0f + t);
}

// byte offset into an fp16 plane [256 rows][128 k]; row stride 256 B;
// 16B-granule XOR swizzle
__device__ __forceinline__ int xhb(int m, int k) {
    return ((m << 8) + (k << 1)) ^ ((m & 7) << 4);
}

__global__ __launch_bounds__(TPB, 1) void mlp_fwd(
    const float* __restrict__ inp,
    const uint4* __restrict__ wpk,   // 7 layers x [term][s*7+t][lane], bias at k=100
    const float* __restrict__ W0, const float* __restrict__ b0,
    const float* __restrict__ W8, const float* __restrict__ b8,
    float* __restrict__ out)
{
    __shared__ _Float16 XH[RPB * 128];   // 64 KB hi plane
    __shared__ _Float16 XL[RPB * 128];   // 64 KB lo plane
    __shared__ float inps[RPB * 2];      // 2 KB raw inputs

    const int tid  = threadIdx.x;
    const int lane = tid & 63;
    const int wid  = tid >> 6;           // wave 0..3 -> rows wid*64..+63
    const int g    = lane >> 4;
    const int bid  = blockIdx.x;

    if (tid < RPB) {
        float2 v = *reinterpret_cast<const float2*>(inp + ((size_t)bid * RPB + tid) * 2);
        inps[tid * 2]     = v.x;
        inps[tid * 2 + 1] = v.y;
    }

    // L0 weights for this thread's 4 columns, from global (registers, no LDS)
    const int q = tid & 31;              // cols 4q..4q+3
    float w00[4], w01[4], b0v[4];
#pragma unroll
    for (int p = 0; p < 4; ++p) {
        int c = 4 * q + p;
        if (c < 100) {
            float2 w2 = *reinterpret_cast<const float2*>(W0 + 2 * c);
            w00[p] = w2.x; w01[p] = w2.y; b0v[p] = b0[c];
        } else { w00[p] = 0.f; w01[p] = 0.f; b0v[p] = 0.f; }
    }
    __syncthreads();   // the only barrier

    // ---- L0: [2 -> 100]; col 100 = 1.0; pad 0.  thread: cols 4q..4q+3,
    //      rows (tid>>5) + 8j  (32 lanes share a row -> inps reads broadcast)
#pragma unroll 4
    for (int j = 0; j < 32; ++j) {
        int r = (tid >> 5) + 8 * j;
        float i0 = inps[r * 2], i1 = inps[r * 2 + 1];
        half4v hh, hl;
#pragma unroll
        for (int p = 0; p < 4; ++p) {
            int c = 4 * q + p;
            float y = (c < 100)
                ? sp100(fmaf(i0, w00[p], fmaf(i1, w01[p], b0v[p])))
                : ((c == 100) ? 1.0f : 0.0f);
            _Float16 h = (_Float16)y;
            hh[p] = h;
            hl[p] = (_Float16)(y - (float)h);
        }
        *reinterpret_cast<half4v*>(reinterpret_cast<char*>(XH) + xhb(r, 4 * q)) = hh;
        *reinterpret_cast<half4v*>(reinterpret_cast<char*>(XL) + xhb(r, 4 * q)) = hl;
    }

    const half8* __restrict__ w8p = reinterpret_cast<const half8*>(wpk);

    // ---- layers 1..7, no barriers (wave-private rows) ----
#pragma unroll 1
    for (int l = 1; l <= 7; ++l) {
        const half8* __restrict__ wl = w8p + (size_t)(l - 1) * 3584;

        f32x4 acc[4][7];
#pragma unroll
        for (int rt = 0; rt < 4; ++rt)
#pragma unroll
            for (int t = 0; t < 7; ++t) acc[rt][t] = f32x4{0.f, 0.f, 0.f, 0.f};

#pragma unroll
        for (int s = 0; s < 4; ++s) {
            // X fragments for 4 row-tiles (LDS)
            half8 xh[4], xl[4];
#pragma unroll
            for (int rt = 0; rt < 4; ++rt) {
                int m  = wid * 64 + rt * 16 + (lane & 15);
                int k0 = s * 32 + g * 8;
                xh[rt] = *reinterpret_cast<const half8*>(
                             reinterpret_cast<const char*>(XH) + xhb(m, k0));
                xl[rt] = *reinterpret_cast<const half8*>(
                             reinterpret_cast<const char*>(XL) + xhb(m, k0));
            }
            // W fragments (L2-resident stream)
            half8 wh[7], wlo[7];
#pragma unroll
            for (int t = 0; t < 7; ++t) {
                wh[t]  = wl[(s * 7 + t) * 64 + lane];
                wlo[t] = wl[1792 + (s * 7 + t) * 64 + lane];
            }
            // term-outer MFMA stream: 28 independent ops per term
#pragma unroll
            for (int t = 0; t < 7; ++t)
#pragma unroll
                for (int rt = 0; rt < 4; ++rt)
                    acc[rt][t] = __builtin_amdgcn_mfma_f32_16x16x32_f16(
                        wh[t], xh[rt], acc[rt][t], 0, 0, 0);
#pragma unroll
            for (int t = 0; t < 7; ++t)
#pragma unroll
                for (int rt = 0; rt < 4; ++rt)
                    acc[rt][t] = __builtin_amdgcn_mfma_f32_16x16x32_f16(
                        wh[t], xl[rt], acc[rt][t], 0, 0, 0);
#pragma unroll
            for (int t = 0; t < 7; ++t)
#pragma unroll
                for (int rt = 0; rt < 4; ++rt)
                    acc[rt][t] = __builtin_amdgcn_mfma_f32_16x16x32_f16(
                        wlo[t], xh[rt], acc[rt][t], 0, 0, 0);
        }

        if (l < 7) {
            const int Nl = (l == 3) ? 98 : 100;
#pragma unroll
            for (int rt = 0; rt < 4; ++rt) {
                int m = wid * 64 + rt * 16 + (lane & 15);
#pragma unroll
                for (int t = 0; t < 7; ++t) {
                    half4v hh, hl;
#pragma unroll
                    for (int i = 0; i < 4; ++i) {
                        int n = 16 * t + 4 * g + i;
                        float y = (n < Nl) ? sp100(acc[rt][t][i])
                                           : ((n == Nl) ? 1.0f : 0.0f);
                        _Float16 h = (_Float16)y;
                        hh[i] = h;
                        hl[i] = (_Float16)(y - (float)h);
                    }
                    if (l != 3) {
                        *reinterpret_cast<half4v*>(
                            reinterpret_cast<char*>(XH) + xhb(m, 16 * t + 4 * g)) = hh;
                        *reinterpret_cast<half4v*>(
                            reinterpret_cast<char*>(XL) + xhb(m, 16 * t + 4 * g)) = hl;
                    } else {   // col shift +2 crosses 16B granules: scalar b16
#pragma unroll
                        for (int i = 0; i < 4; ++i) {
                            int c = 16 * t + 4 * g + i + 2;
                            *reinterpret_cast<_Float16*>(
                                reinterpret_cast<char*>(XH) + xhb(m, c)) = hh[i];
                            *reinterpret_cast<_Float16*>(
                                reinterpret_cast<char*>(XL) + xhb(m, c)) = hl[i];
                        }
                    }
                }
            }
            if (l == 3) {   // skip-concat: raw inputs -> cols 0,1 (own rows)
                int m = wid * 64 + lane;
#pragma unroll
                for (int c = 0; c < 2; ++c) {
                    float v = inps[m * 2 + c];
                    _Float16 h = (_Float16)v;
                    *reinterpret_cast<_Float16*>(
                        reinterpret_cast<char*>(XH) + xhb(m, c)) = h;
                    *reinterpret_cast<_Float16*>(
                        reinterpret_cast<char*>(XL) + xhb(m, c)) = (_Float16)(v - (float)h);
                }
            }
        } else {
            // ---- fused L8: dot with W8 (b7 already inside acc), reduce ----
            float w84[7][4];
#pragma unroll
            for (int t = 0; t < 6; ++t) {
                float4 w4 = *reinterpret_cast<const float4*>(W8 + 16 * t + 4 * g);
                w84[t][0] = w4.x; w84[t][1] = w4.y; w84[t][2] = w4.z; w84[t][3] = w4.w;
            }
#pragma unroll
            for (int i = 0; i < 4; ++i) {
                int n = 96 + 4 * g + i;
                w84[6][i] = (n < 100) ? W8[n] : 0.0f;
            }
            float b8v = b8[0];
#pragma unroll
            for (int rt = 0; rt < 4; ++rt) {
                float p8 = 0.0f;
#pragma unroll
                for (int t = 0; t < 7; ++t)
#pragma unroll
                    for (int i = 0; i < 4; ++i)
                        p8 = fmaf(w84[t][i], sp100(acc[rt][t][i]), p8);
                p8 += __shfl_xor(p8, 16);
                p8 += __shfl_xor(p8, 32);
                if (lane < 16)
                    out[(size_t)bid * RPB + wid * 64 + rt * 16 + lane] = p8 + b8v;
            }
        }
    }
}

// Pack W1..W7 (+ biases b1..b7 at k=100) -> per-layer [term][s*7+t][lane] half8:
// half jj at k=32s+8*(lane>>4)+jj, n=16t+(lane&15);
//   k<100: W[n][k];  k==100: b[n];  else 0.  (zero outside n<Nl)
// term0=(f16)val, term1=(f16)(val-(float)(f16)val).
__global__ void pack_weights(
    const float* __restrict__ W1, const float* __restrict__ W2,
    const float* __restrict__ W3, const float* __restrict__ W4,
    const float* __restrict__ W5, const float* __restrict__ W6,
    const float* __restrict__ W7,
    const float* __restrict__ b1, const float* __restrict__ b2,
    const float* __restrict__ b3, const float* __restrict__ b4,
    const float* __restrict__ b5, const float* __restrict__ b6,
    const float* __restrict__ b7,
    uint4* __restrict__ wpk)
{
    const float* Wt[7] = {W1, W2, W3, W4, W5, W6, W7};
    const float* Bt[7] = {b1, b2, b3, b4, b5, b6, b7};
    const float* W = Wt[blockIdx.x];
    const float* B = Bt[blockIdx.x];
    const int Nl = (blockIdx.x == 2) ? 98 : 100;   // layer 3 outputs 98
    for (int e = threadIdx.x; e < 3584; e += 256) {
        int term = e / 1792;
        int r    = e - term * 1792;
        int lane = r & 63;
        int st   = r >> 6;
        int s    = st / 7;
        int t    = st - s * 7;
        union { _Float16 h[8]; uint4 v; } pk;
#pragma unroll
        for (int jj = 0; jj < 8; ++jj) {
            int k = s * 32 + (lane >> 4) * 8 + jj;
            int n = t * 16 + (lane & 15);
            float val = 0.0f;
            if (n < Nl) {
                if (k < 100)       val = W[n * 100 + k];
                else if (k == 100) val = B[n];
            }
            _Float16 h = (_Float16)val;
            pk.h[jj] = term ? (_Float16)(val - (float)h) : h;
        }
        wpk[blockIdx.x * 3584 + term * 1792 + r] = pk.v;
    }
}

extern "C" void kernel_launch(void* const* d_in, const int* in_sizes, int n_in,
                              void* d_out, int out_size, void* d_ws, size_t ws_size,
                              hipStream_t stream)
{
    const float* inp = (const float*)d_in[0];
    const float* W[9];
    const float* B[9];
    for (int l = 0; l < 9; ++l) {
        W[l] = (const float*)d_in[1 + 2 * l];
        B[l] = (const float*)d_in[2 + 2 * l];
    }
    uint4* wpk = (uint4*)d_ws;             // 7*3584*16 = 401,408 B
    float* out = (float*)d_out;
    const int N = in_sizes[0] / 2;         // 1,048,576 rows

    pack_weights<<<7, 256, 0, stream>>>(W[1], W[2], W[3], W[4], W[5], W[6], W[7],
                                        B[1], B[2], B[3], B[4], B[5], B[6], B[7],
                                        wpk);
    mlp_fwd<<<N / RPB, TPB, 0, stream>>>(inp, wpk,
                                         W[0], B[0], W[8], B[8],
                                         out);
}

// Round 13
// 717.599 us; speedup vs baseline: 1.3751x; 1.3751x over previous
//
#include <hip/hip_runtime.h>
#include <math.h>

// Round 13: r12 resubmit with cvt_pkrtz type fix (__fp16x2 return type).
//  (1) per-layer __syncthreads(): 4 waves phase-locked -> identical W-streams
//      coalesce in L1/MSHR instead of 4 separate L2 round trips. Also closes
//      the L0 cross-wave race.
//  (2) v_cvt_pkrtz hi/lo split: fewer VALU ops per 4 elems.
//  (3) L0 with W0 in registers from global.
// Carried from r9: 256 thr / 4 waves / 128 rows, rt=2, split-fp16 3-term,
// bias folded at k=100 (X col 100 == 1.0), HW transcendentals, hi/lo fp16
// planes with ((m&7)<<4) XOR swizzle, term-outer MFMA stream.

typedef _Float16 half8 __attribute__((ext_vector_type(8)));
typedef _Float16 half4v __attribute__((ext_vector_type(4)));
typedef __fp16 fp16x2 __attribute__((ext_vector_type(2)));
typedef float f32x4 __attribute__((ext_vector_type(4)));

#define TPB 256
#define RPB 128

__device__ __forceinline__ float sp100(float x) {
    // softplus(100x)/100 = max(x,0) + ln2/100 * log2(1 + 2^(-(100/ln2)*|x|))
    float t = __builtin_amdgcn_exp2f(-144.26950408889634f * fabsf(x));
    return fmaxf(x, 0.0f) + 0.0069314718055994531f * __builtin_amdgcn_logf(1.0f + t);
}

// byte offset into an fp16 plane [128 rows][128 k]; row stride 256 B;
// 16B-granule XOR swizzle
__device__ __forceinline__ int xhb(int m, int k) {
    return ((m << 8) + (k << 1)) ^ ((m & 7) << 4);
}

// split 4 f32 -> hi/lo fp16 quads via v_cvt_pkrtz
__device__ __forceinline__ void split4(const float y[4], half4v &hh, half4v &hl) {
    union { fp16x2 h2[2]; half4v h4; } H, L;
    H.h2[0] = __builtin_amdgcn_cvt_pkrtz(y[0], y[1]);
    H.h2[1] = __builtin_amdgcn_cvt_pkrtz(y[2], y[3]);
    float d0 = y[0] - (float)H.h2[0][0];
    float d1 = y[1] - (float)H.h2[0][1];
    float d2 = y[2] - (float)H.h2[1][0];
    float d3 = y[3] - (float)H.h2[1][1];
    L.h2[0] = __builtin_amdgcn_cvt_pkrtz(d0, d1);
    L.h2[1] = __builtin_amdgcn_cvt_pkrtz(d2, d3);
    hh = H.h4; hl = L.h4;
}

__global__ __launch_bounds__(TPB, 2) void mlp_fwd(
    const float* __restrict__ inp,
    const uint4* __restrict__ wpk,   // 7 layers x [term][s*7+t][lane], bias at k=100
    const float* __restrict__ W0, const float* __restrict__ b0,
    const float* __restrict__ W8, const float* __restrict__ b8,
    float* __restrict__ out)
{
    __shared__ _Float16 XH[RPB * 128];   // 32 KB hi plane
    __shared__ _Float16 XL[RPB * 128];   // 32 KB lo plane
    __shared__ float inps[RPB * 2];

    const int tid  = threadIdx.x;
    const int lane = tid & 63;
    const int wid  = tid >> 6;           // wave 0..3 -> rows wid*32..+31
    const int g    = lane >> 4;
    const int bid  = blockIdx.x;

    if (tid < RPB) {
        float2 v = *reinterpret_cast<const float2*>(inp + ((size_t)bid * RPB + tid) * 2);
        inps[tid * 2]     = v.x;
        inps[tid * 2 + 1] = v.y;
    }

    // L0 weights for this thread's 4 columns, from global (regs, no LDS)
    const int q = tid & 31;              // cols 4q..4q+3
    float w00[4], w01[4], b0v[4];
#pragma unroll
    for (int p = 0; p < 4; ++p) {
        int c = 4 * q + p;
        if (c < 100) {
            float2 w2 = *reinterpret_cast<const float2*>(W0 + 2 * c);
            w00[p] = w2.x; w01[p] = w2.y; b0v[p] = b0[c];
        } else { w00[p] = 0.f; w01[p] = 0.f; b0v[p] = 0.f; }
    }
    __syncthreads();   // inps ready

    // ---- L0: [2 -> 100]; col 100 = 1.0; pad 0. thread: cols 4q..4q+3,
    //      rows (tid>>5)+8j (32 lanes share a row -> broadcast reads) ----
#pragma unroll 2
    for (int j = 0; j < 16; ++j) {
        int r = (tid >> 5) + 8 * j;
        float i0 = inps[r * 2], i1 = inps[r * 2 + 1];
        float y[4];
#pragma unroll
        for (int p = 0; p < 4; ++p) {
            int c = 4 * q + p;
            y[p] = (c < 100)
                ? sp100(fmaf(i0, w00[p], fmaf(i1, w01[p], b0v[p])))
                : ((c == 100) ? 1.0f : 0.0f);
        }
        half4v hh, hl;
        split4(y, hh, hl);
        *reinterpret_cast<half4v*>(reinterpret_cast<char*>(XH) + xhb(r, 4 * q)) = hh;
        *reinterpret_cast<half4v*>(reinterpret_cast<char*>(XL) + xhb(r, 4 * q)) = hl;
    }

    const half8* __restrict__ w8p = reinterpret_cast<const half8*>(wpk);

    // ---- layers 1..7 ----
#pragma unroll 1
    for (int l = 1; l <= 7; ++l) {
        __syncthreads();   // (a) L0/epilogue writes visible (b) W-stream lockstep
        const half8* __restrict__ wl = w8p + (size_t)(l - 1) * 3584;

        f32x4 acc[2][7];
#pragma unroll
        for (int rt = 0; rt < 2; ++rt)
#pragma unroll
            for (int t = 0; t < 7; ++t) acc[rt][t] = f32x4{0.f, 0.f, 0.f, 0.f};

#pragma unroll
        for (int s = 0; s < 4; ++s) {
            half8 xh[2], xl[2];
#pragma unroll
            for (int rt = 0; rt < 2; ++rt) {
                int m  = wid * 32 + rt * 16 + (lane & 15);
                int k0 = s * 32 + g * 8;
                xh[rt] = *reinterpret_cast<const half8*>(
                             reinterpret_cast<const char*>(XH) + xhb(m, k0));
                xl[rt] = *reinterpret_cast<const half8*>(
                             reinterpret_cast<const char*>(XL) + xhb(m, k0));
            }
            half8 wh[7], wlo[7];
#pragma unroll
            for (int t = 0; t < 7; ++t) {
                wh[t]  = wl[(s * 7 + t) * 64 + lane];
                wlo[t] = wl[1792 + (s * 7 + t) * 64 + lane];
            }
            // term-outer MFMA stream: 14 independent chains per term
#pragma unroll
            for (int t = 0; t < 7; ++t)
#pragma unroll
                for (int rt = 0; rt < 2; ++rt)
                    acc[rt][t] = __builtin_amdgcn_mfma_f32_16x16x32_f16(
                        wh[t], xh[rt], acc[rt][t], 0, 0, 0);
#pragma unroll
            for (int t = 0; t < 7; ++t)
#pragma unroll
                for (int rt = 0; rt < 2; ++rt)
                    acc[rt][t] = __builtin_amdgcn_mfma_f32_16x16x32_f16(
                        wh[t], xl[rt], acc[rt][t], 0, 0, 0);
#pragma unroll
            for (int t = 0; t < 7; ++t)
#pragma unroll
                for (int rt = 0; rt < 2; ++rt)
                    acc[rt][t] = __builtin_amdgcn_mfma_f32_16x16x32_f16(
                        wlo[t], xh[rt], acc[rt][t], 0, 0, 0);
        }

        if (l < 7) {
            const int Nl = (l == 3) ? 98 : 100;
#pragma unroll
            for (int rt = 0; rt < 2; ++rt) {
                int m = wid * 32 + rt * 16 + (lane & 15);
#pragma unroll
                for (int t = 0; t < 7; ++t) {
                    float y[4];
#pragma unroll
                    for (int i = 0; i < 4; ++i) {
                        int n = 16 * t + 4 * g + i;
                        y[i] = (n < Nl) ? sp100(acc[rt][t][i])
                                        : ((n == Nl) ? 1.0f : 0.0f);
                    }
                    half4v hh, hl;
                    split4(y, hh, hl);
                    if (l != 3) {
                        *reinterpret_cast<half4v*>(
                            reinterpret_cast<char*>(XH) + xhb(m, 16 * t + 4 * g)) = hh;
                        *reinterpret_cast<half4v*>(
                            reinterpret_cast<char*>(XL) + xhb(m, 16 * t + 4 * g)) = hl;
                    } else {   // col shift +2 crosses 16B granules: scalar b16
#pragma unroll
                        for (int i = 0; i < 4; ++i) {
                            int c = 16 * t + 4 * g + i + 2;
                            *reinterpret_cast<_Float16*>(
                                reinterpret_cast<char*>(XH) + xhb(m, c)) = hh[i];
                            *reinterpret_cast<_Float16*>(
                                reinterpret_cast<char*>(XL) + xhb(m, c)) = hl[i];
                        }
                    }
                }
            }
            if (l == 3 && lane < 32) {   // skip-concat: inputs -> cols 0,1
                int m = wid * 32 + lane;
#pragma unroll
                for (int c = 0; c < 2; ++c) {
                    float v = inps[m * 2 + c];
                    _Float16 h = (_Float16)v;
                    *reinterpret_cast<_Float16*>(
                        reinterpret_cast<char*>(XH) + xhb(m, c)) = h;
                    *reinterpret_cast<_Float16*>(
                        reinterpret_cast<char*>(XL) + xhb(m, c)) = (_Float16)(v - (float)h);
                }
            }
        } else {
            // ---- fused L8: dot with W8 (b7 already inside acc), reduce ----
            float w84[7][4];
#pragma unroll
            for (int t = 0; t < 6; ++t) {
                float4 w4 = *reinterpret_cast<const float4*>(W8 + 16 * t + 4 * g);
                w84[t][0] = w4.x; w84[t][1] = w4.y; w84[t][2] = w4.z; w84[t][3] = w4.w;
            }
#pragma unroll
            for (int i = 0; i < 4; ++i) {
                int n = 96 + 4 * g + i;
                w84[6][i] = (n < 100) ? W8[n] : 0.0f;
            }
            float b8v = b8[0];
#pragma unroll
            for (int rt = 0; rt < 2; ++rt) {
                float p8 = 0.0f;
#pragma unroll
                for (int t = 0; t < 7; ++t)
#pragma unroll
                    for (int i = 0; i < 4; ++i)
                        p8 = fmaf(w84[t][i], sp100(acc[rt][t][i]), p8);
                p8 += __shfl_xor(p8, 16);
                p8 += __shfl_xor(p8, 32);
                if (lane < 16)
                    out[(size_t)bid * RPB + wid * 32 + rt * 16 + lane] = p8 + b8v;
            }
        }
    }
}

// Pack W1..W7 (+ biases b1..b7 at k=100) -> per-layer [term][s*7+t][lane] half8:
// half jj at k=32s+8*(lane>>4)+jj, n=16t+(lane&15);
//   k<100: W[n][k];  k==100: b[n];  else 0.  (zero outside n<Nl)
// term0=(f16)val (RNE), term1=(f16)(val-(float)(f16)val).
__global__ void pack_weights(
    const float* __restrict__ W1, const float* __restrict__ W2,
    const float* __restrict__ W3, const float* __restrict__ W4,
    const float* __restrict__ W5, const float* __restrict__ W6,
    const float* __restrict__ W7,
    const float* __restrict__ b1, const float* __restrict__ b2,
    const float* __restrict__ b3, const float* __restrict__ b4,
    const float* __restrict__ b5, const float* __restrict__ b6,
    const float* __restrict__ b7,
    uint4* __restrict__ wpk)
{
    const float* Wt[7] = {W1, W2, W3, W4, W5, W6, W7};
    const float* Bt[7] = {b1, b2, b3, b4, b5, b6, b7};
    const float* W = Wt[blockIdx.x];
    const float* B = Bt[blockIdx.x];
    const int Nl = (blockIdx.x == 2) ? 98 : 100;   // layer 3 outputs 98
    for (int e = threadIdx.x; e < 3584; e += 256) {
        int term = e / 1792;
        int r    = e - term * 1792;
        int lane = r & 63;
        int st   = r >> 6;
        int s    = st / 7;
        int t    = st - s * 7;
        union { _Float16 h[8]; uint4 v; } pk;
#pragma unroll
        for (int jj = 0; jj < 8; ++jj) {
            int k = s * 32 + (lane >> 4) * 8 + jj;
            int n = t * 16 + (lane & 15);
            float val = 0.0f;
            if (n < Nl) {
                if (k < 100)       val = W[n * 100 + k];
                else if (k == 100) val = B[n];
            }
            _Float16 h = (_Float16)val;
            pk.h[jj] = term ? (_Float16)(val - (float)h) : h;
        }
        wpk[blockIdx.x * 3584 + term * 1792 + r] = pk.v;
    }
}

extern "C" void kernel_launch(void* const* d_in, const int* in_sizes, int n_in,
                              void* d_out, int out_size, void* d_ws, size_t ws_size,
                              hipStream_t stream)
{
    const float* inp = (const float*)d_in[0];
    const float* W[9];
    const float* B[9];
    for (int l = 0; l < 9; ++l) {
        W[l] = (const float*)d_in[1 + 2 * l];
        B[l] = (const float*)d_in[2 + 2 * l];
    }
    uint4* wpk = (uint4*)d_ws;             // 7*3584*16 = 401,408 B
    float* out = (float*)d_out;
    const int N = in_sizes[0] / 2;         // 1,048,576 rows

    pack_weights<<<7, 256, 0, stream>>>(W[1], W[2], W[3], W[4], W[5], W[6], W[7],
                                        B[1], B[2], B[3], B[4], B[5], B[6], B[7],
                                        wpk);
    mlp_fwd<<<N / RPB, TPB, 0, stream>>>(inp, wpk,
                                         W[0], B[0], W[8], B[8],
                                         out);
}

// Round 14
// 687.715 us; speedup vs baseline: 1.4348x; 1.0435x over previous
//
#include <hip/hip_runtime.h>
#include <math.h>

// Round 14: r13 + LDS address strength reduction.
//   The 440us of VALU issue (53% x 830us) is dominated by per-access xhb()
//   swizzle math (shift+or+xor per ds op) -- the XOR swizzle's bit-6 overlap
//   prevented offset-immediate folding. Replace with 272B row stride
//   (17 granules, odd -> rows rotate bank positions mod 8; reads stay at the
//   wave64-b128 floor, writes 2-way=free). All X accesses now: one per-lane
//   base VGPR + compile-time 'offset:' immediates (rt*4352 + s*64 + t*32 +
//   plane*34816). Single fused X2 buffer so hi/lo planes share a base.
// Carried from r13: 256 thr / 4 waves / 128 rows, rt=2, split-fp16 3-term,
// bias folded at k=100 (X col 100 == 1.0), HW transcendentals, pkrtz split,
// per-layer barrier (W-stream lockstep), L0 weights in registers, term-outer
// MFMA stream, fused L8.

typedef _Float16 half8 __attribute__((ext_vector_type(8)));
typedef _Float16 half4v __attribute__((ext_vector_type(4)));
typedef __fp16 fp16x2 __attribute__((ext_vector_type(2)));
typedef float f32x4 __attribute__((ext_vector_type(4)));

#define TPB 256
#define RPB 128
#define RSTRIDE 272                      // bytes per row (17 x 16B granules)
#define PLANE   (RPB * RSTRIDE)          // 34816 B per plane

__device__ __forceinline__ float sp100(float x) {
    // softplus(100x)/100 = max(x,0) + ln2/100 * log2(1 + 2^(-(100/ln2)*|x|))
    float t = __builtin_amdgcn_exp2f(-144.26950408889634f * fabsf(x));
    return fmaxf(x, 0.0f) + 0.0069314718055994531f * __builtin_amdgcn_logf(1.0f + t);
}

// split 4 f32 -> hi/lo fp16 quads via v_cvt_pkrtz
__device__ __forceinline__ void split4(const float y[4], half4v &hh, half4v &hl) {
    union { fp16x2 h2[2]; half4v h4; } H, L;
    H.h2[0] = __builtin_amdgcn_cvt_pkrtz(y[0], y[1]);
    H.h2[1] = __builtin_amdgcn_cvt_pkrtz(y[2], y[3]);
    float d0 = y[0] - (float)H.h2[0][0];
    float d1 = y[1] - (float)H.h2[0][1];
    float d2 = y[2] - (float)H.h2[1][0];
    float d3 = y[3] - (float)H.h2[1][1];
    L.h2[0] = __builtin_amdgcn_cvt_pkrtz(d0, d1);
    L.h2[1] = __builtin_amdgcn_cvt_pkrtz(d2, d3);
    hh = H.h4; hl = L.h4;
}

__global__ __launch_bounds__(TPB, 2) void mlp_fwd(
    const float* __restrict__ inp,
    const uint4* __restrict__ wpk,   // 7 layers x [term][s*7+t][lane], bias at k=100
    const float* __restrict__ W0, const float* __restrict__ b0,
    const float* __restrict__ W8, const float* __restrict__ b8,
    float* __restrict__ out)
{
    __shared__ _Float16 X2[2 * RPB * (RSTRIDE / 2)];  // 69,632 B: XH @0, XL @+34816B
    __shared__ float inps[RPB * 2];

    const int tid  = threadIdx.x;
    const int lane = tid & 63;
    const int wid  = tid >> 6;           // wave 0..3 -> rows wid*32..+31
    const int g    = lane >> 4;
    const int bid  = blockIdx.x;

    if (tid < RPB) {
        float2 v = *reinterpret_cast<const float2*>(inp + ((size_t)bid * RPB + tid) * 2);
        inps[tid * 2]     = v.x;
        inps[tid * 2 + 1] = v.y;
    }

    // L0 weights for this thread's 4 columns, from global (regs, no LDS)
    const int q = tid & 31;              // cols 4q..4q+3
    float w00[4], w01[4], b0v[4];
#pragma unroll
    for (int p = 0; p < 4; ++p) {
        int c = 4 * q + p;
        if (c < 100) {
            float2 w2 = *reinterpret_cast<const float2*>(W0 + 2 * c);
            w00[p] = w2.x; w01[p] = w2.y; b0v[p] = b0[c];
        } else { w00[p] = 0.f; w01[p] = 0.f; b0v[p] = 0.f; }
    }
    __syncthreads();   // inps ready

    // ---- L0: [2 -> 100]; col 100 = 1.0; pad 0. thread: cols 4q..4q+3,
    //      rows (tid>>5)+8j. Bases: one per plane, immediates j*2176. ----
    {
        char* l0h = reinterpret_cast<char*>(X2) + (tid >> 5) * RSTRIDE + 8 * q;
        char* l0l = l0h + PLANE;
#pragma unroll 2
        for (int j = 0; j < 16; ++j) {
            int r = (tid >> 5) + 8 * j;
            float i0 = inps[r * 2], i1 = inps[r * 2 + 1];
            float y[4];
#pragma unroll
            for (int p = 0; p < 4; ++p) {
                int c = 4 * q + p;
                y[p] = (c < 100)
                    ? sp100(fmaf(i0, w00[p], fmaf(i1, w01[p], b0v[p])))
                    : ((c == 100) ? 1.0f : 0.0f);
            }
            half4v hh, hl;
            split4(y, hh, hl);
            *reinterpret_cast<half4v*>(l0h + j * (8 * RSTRIDE)) = hh;
            *reinterpret_cast<half4v*>(l0l + j * (8 * RSTRIDE)) = hl;
        }
    }

    const half8* __restrict__ w8p = reinterpret_cast<const half8*>(wpk);

    // per-lane LDS bases (all rt/s/t/plane offsets are compile-time imms)
    const char* xrd = reinterpret_cast<const char*>(X2)
                      + (wid * 32 + (lane & 15)) * RSTRIDE + g * 16;
    char*       xwr = reinterpret_cast<char*>(X2)
                      + (wid * 32 + (lane & 15)) * RSTRIDE + g * 8;

    // ---- layers 1..7 ----
#pragma unroll 1
    for (int l = 1; l <= 7; ++l) {
        __syncthreads();   // (a) prior writes visible (b) W-stream lockstep
        const half8* __restrict__ wl = w8p + (size_t)(l - 1) * 3584;

        f32x4 acc[2][7];
#pragma unroll
        for (int rt = 0; rt < 2; ++rt)
#pragma unroll
            for (int t = 0; t < 7; ++t) acc[rt][t] = f32x4{0.f, 0.f, 0.f, 0.f};

#pragma unroll
        for (int s = 0; s < 4; ++s) {
            half8 xh[2], xl[2];
#pragma unroll
            for (int rt = 0; rt < 2; ++rt) {
                xh[rt] = *reinterpret_cast<const half8*>(xrd + rt * 4352 + s * 64);
                xl[rt] = *reinterpret_cast<const half8*>(xrd + rt * 4352 + s * 64 + PLANE);
            }
            half8 wh[7], wlo[7];
#pragma unroll
            for (int t = 0; t < 7; ++t) {
                wh[t]  = wl[(s * 7 + t) * 64 + lane];
                wlo[t] = wl[1792 + (s * 7 + t) * 64 + lane];
            }
            // term-outer MFMA stream: 14 independent chains per term
#pragma unroll
            for (int t = 0; t < 7; ++t)
#pragma unroll
                for (int rt = 0; rt < 2; ++rt)
                    acc[rt][t] = __builtin_amdgcn_mfma_f32_16x16x32_f16(
                        wh[t], xh[rt], acc[rt][t], 0, 0, 0);
#pragma unroll
            for (int t = 0; t < 7; ++t)
#pragma unroll
                for (int rt = 0; rt < 2; ++rt)
                    acc[rt][t] = __builtin_amdgcn_mfma_f32_16x16x32_f16(
                        wh[t], xl[rt], acc[rt][t], 0, 0, 0);
#pragma unroll
            for (int t = 0; t < 7; ++t)
#pragma unroll
                for (int rt = 0; rt < 2; ++rt)
                    acc[rt][t] = __builtin_amdgcn_mfma_f32_16x16x32_f16(
                        wlo[t], xh[rt], acc[rt][t], 0, 0, 0);
        }

        if (l < 7) {
            const int Nl = (l == 3) ? 98 : 100;
#pragma unroll
            for (int rt = 0; rt < 2; ++rt) {
#pragma unroll
                for (int t = 0; t < 7; ++t) {
                    float y[4];
#pragma unroll
                    for (int i = 0; i < 4; ++i) {
                        int n = 16 * t + 4 * g + i;
                        y[i] = (n < Nl) ? sp100(acc[rt][t][i])
                                        : ((n == Nl) ? 1.0f : 0.0f);
                    }
                    half4v hh, hl;
                    split4(y, hh, hl);
                    if (l != 3) {
                        *reinterpret_cast<half4v*>(
                            xwr + rt * 4352 + t * 32) = hh;
                        *reinterpret_cast<half4v*>(
                            xwr + rt * 4352 + t * 32 + PLANE) = hl;
                    } else {   // col shift +2 -> byte +4: scalar b16 stores
#pragma unroll
                        for (int i = 0; i < 4; ++i) {
                            *reinterpret_cast<_Float16*>(
                                xwr + rt * 4352 + t * 32 + 2 * i + 4) = hh[i];
                            *reinterpret_cast<_Float16*>(
                                xwr + rt * 4352 + t * 32 + 2 * i + 4 + PLANE) = hl[i];
                        }
                    }
                }
            }
            if (l == 3 && lane < 32) {   // skip-concat: inputs -> cols 0,1
                int m = wid * 32 + lane;
                char* xc = reinterpret_cast<char*>(X2) + m * RSTRIDE;
#pragma unroll
                for (int c = 0; c < 2; ++c) {
                    float v = inps[m * 2 + c];
                    _Float16 h = (_Float16)v;
                    *reinterpret_cast<_Float16*>(xc + 2 * c) = h;
                    *reinterpret_cast<_Float16*>(xc + 2 * c + PLANE) =
                        (_Float16)(v - (float)h);
                }
            }
        } else {
            // ---- fused L8: dot with W8 (b7 already inside acc), reduce ----
            float w84[7][4];
#pragma unroll
            for (int t = 0; t < 6; ++t) {
                float4 w4 = *reinterpret_cast<const float4*>(W8 + 16 * t + 4 * g);
                w84[t][0] = w4.x; w84[t][1] = w4.y; w84[t][2] = w4.z; w84[t][3] = w4.w;
            }
#pragma unroll
            for (int i = 0; i < 4; ++i) {
                int n = 96 + 4 * g + i;
                w84[6][i] = (n < 100) ? W8[n] : 0.0f;
            }
            float b8v = b8[0];
#pragma unroll
            for (int rt = 0; rt < 2; ++rt) {
                float p8 = 0.0f;
#pragma unroll
                for (int t = 0; t < 7; ++t)
#pragma unroll
                    for (int i = 0; i < 4; ++i)
                        p8 = fmaf(w84[t][i], sp100(acc[rt][t][i]), p8);
                p8 += __shfl_xor(p8, 16);
                p8 += __shfl_xor(p8, 32);
                if (lane < 16)
                    out[(size_t)bid * RPB + wid * 32 + rt * 16 + lane] = p8 + b8v;
            }
        }
    }
}

// Pack W1..W7 (+ biases b1..b7 at k=100) -> per-layer [term][s*7+t][lane] half8:
// half jj at k=32s+8*(lane>>4)+jj, n=16t+(lane&15);
//   k<100: W[n][k];  k==100: b[n];  else 0.  (zero outside n<Nl)
// term0=(f16)val (RNE), term1=(f16)(val-(float)(f16)val).
__global__ void pack_weights(
    const float* __restrict__ W1, const float* __restrict__ W2,
    const float* __restrict__ W3, const float* __restrict__ W4,
    const float* __restrict__ W5, const float* __restrict__ W6,
    const float* __restrict__ W7,
    const float* __restrict__ b1, const float* __restrict__ b2,
    const float* __restrict__ b3, const float* __restrict__ b4,
    const float* __restrict__ b5, const float* __restrict__ b6,
    const float* __restrict__ b7,
    uint4* __restrict__ wpk)
{
    const float* Wt[7] = {W1, W2, W3, W4, W5, W6, W7};
    const float* Bt[7] = {b1, b2, b3, b4, b5, b6, b7};
    const float* W = Wt[blockIdx.x];
    const float* B = Bt[blockIdx.x];
    const int Nl = (blockIdx.x == 2) ? 98 : 100;   // layer 3 outputs 98
    for (int e = threadIdx.x; e < 3584; e += 256) {
        int term = e / 1792;
        int r    = e - term * 1792;
        int lane = r & 63;
        int st   = r >> 6;
        int s    = st / 7;
        int t    = st - s * 7;
        union { _Float16 h[8]; uint4 v; } pk;
#pragma unroll
        for (int jj = 0; jj < 8; ++jj) {
            int k = s * 32 + (lane >> 4) * 8 + jj;
            int n = t * 16 + (lane & 15);
            float val = 0.0f;
            if (n < Nl) {
                if (k < 100)       val = W[n * 100 + k];
                else if (k == 100) val = B[n];
            }
            _Float16 h = (_Float16)val;
            pk.h[jj] = term ? (_Float16)(val - (float)h) : h;
        }
        wpk[blockIdx.x * 3584 + term * 1792 + r] = pk.v;
    }
}

extern "C" void kernel_launch(void* const* d_in, const int* in_sizes, int n_in,
                              void* d_out, int out_size, void* d_ws, size_t ws_size,
                              hipStream_t stream)
{
    const float* inp = (const float*)d_in[0];
    const float* W[9];
    const float* B[9];
    for (int l = 0; l < 9; ++l) {
        W[l] = (const float*)d_in[1 + 2 * l];
        B[l] = (const float*)d_in[2 + 2 * l];
    }
    uint4* wpk = (uint4*)d_ws;             // 7*3584*16 = 401,408 B
    float* out = (float*)d_out;
    const int N = in_sizes[0] / 2;         // 1,048,576 rows

    pack_weights<<<7, 256, 0, stream>>>(W[1], W[2], W[3], W[4], W[5], W[6], W[7],
                                        B[1], B[2], B[3], B[4], B[5], B[6], B[7],
                                        wpk);
    mlp_fwd<<<N / RPB, TPB, 0, stream>>>(inp, wpk,
                                         W[0], B[0], W[8], B[8],
                                         out);
}